// Round 1
// baseline (2467.070 us; speedup 1.0000x reference)
//
#include <hip/hip_runtime.h>
#include <hip/hip_fp16.h>

typedef _Float16 half8 __attribute__((ext_vector_type(8)));
typedef _Float16 half4v __attribute__((ext_vector_type(4)));
typedef float f32x4 __attribute__((ext_vector_type(4)));

#define T_INS 200
#define HDIM 128
#define NB 16

// LDS byte offsets
constexpr int H0O = 0;       // 2 x 4096 (parity)
constexpr int H1O = 8192;    // 2 x 4096
constexpr int XTO = 16384;   // 2 x 4096
constexpr int BIO = 24576;   // float[2][512]
constexpr int SMSZ = 24576 + 4096;

// swizzled [batch][k] f16 layout: 2-way-max bank aliasing for b128 reads
#define OFF(b, k) (((((b) << 8) | ((k) << 1))) ^ (((b) & 7) << 4))

__device__ __forceinline__ float sigm(float x) {
  return __builtin_amdgcn_rcpf(1.0f + __builtin_amdgcn_exp2f(-1.44269504f * x));
}
__device__ __forceinline__ float tanh_f(float x) {
  return 1.0f - 2.0f * __builtin_amdgcn_rcpf(1.0f + __builtin_amdgcn_exp2f(2.88539008f * x));
}
__device__ __forceinline__ half8 cvt_frag(const float* __restrict__ src) {
  f32x4 a = *(const f32x4*)src;
  f32x4 b = *(const f32x4*)(src + 4);
  half8 h;
  h[0] = (_Float16)a[0]; h[1] = (_Float16)a[1]; h[2] = (_Float16)a[2]; h[3] = (_Float16)a[3];
  h[4] = (_Float16)b[0]; h[5] = (_Float16)b[1]; h[6] = (_Float16)b[2]; h[7] = (_Float16)b[3];
  return h;
}

// Pack W_ih (both layers) into per-(wave,Mtile,Kfrag) f16 MFMA A-fragments in ws.
// Frag F = (l*8 + w)*16 + mt*4 + kf ; 64 lanes x 16B each.
// Row permutation: perm_row = unit*4 + gate  ->  orig_row = gate*128 + unit.
__global__ __launch_bounds__(256) void pack_kernel(const float* __restrict__ W_ih,
                                                   char* __restrict__ ws) {
  int gid = blockIdx.x * 256 + threadIdx.x;   // 16384 threads exactly
  int F = gid >> 6, lane = gid & 63;
  int l = F >> 7, w = (F >> 4) & 7, mt = (F >> 2) & 3, kf = F & 3;
  int rp = w * 64 + mt * 16 + (lane & 15);
  int row = (rp & 3) * 128 + (rp >> 2);
  int k0 = kf * 32 + (lane >> 4) * 8;
  const float* src = W_ih + (size_t)(l * 512 + row) * 128 + k0;
  *(half8*)(ws + (size_t)F * 1024 + lane * 16) = cvt_frag(src);
}

__global__ __launch_bounds__(512, 2) void lstm_kernel(
    const float* __restrict__ x, const int* __restrict__ len_in,
    const int* __restrict__ len_ar, const float* __restrict__ W_ih,
    const float* __restrict__ W_hh, const float* __restrict__ b_ih,
    const float* __restrict__ b_hh, const char* __restrict__ ws,
    float* __restrict__ out, int packed) {
  __shared__ __attribute__((aligned(16))) char sm[SMSZ];
  float* biasS = (float*)(sm + BIO);

  const int tid = threadIdx.x;
  const int w = tid >> 6, lane = tid & 63;
  const int lb = lane & 15, lg = lane >> 4;
  const int k0b = lg * 8;
  const int batch = blockIdx.x * NB + lb;
  const int Lin = len_in[batch];
  const int Lar = len_ar[batch];

  // per-Mtile original row index for this lane (A-frag row = lane&15 within tile)
  int rowi[4];
#pragma unroll
  for (int mt = 0; mt < 4; ++mt) {
    int rp = w * 64 + mt * 16 + lb;
    rowi[mt] = (rp & 3) * 128 + (rp >> 2);
  }

  // resident recurrent weights W_hh[0],W_hh[1] as A-frags (128 VGPRs/lane)
  half8 whh[2][4][4];
#pragma unroll
  for (int l = 0; l < 2; ++l)
#pragma unroll
    for (int mt = 0; mt < 4; ++mt)
#pragma unroll
      for (int kf = 0; kf < 4; ++kf)
        whh[l][mt][kf] =
            cvt_frag(W_hh + (size_t)(l * 512 + rowi[mt]) * 128 + kf * 32 + k0b);

  // biases (gate-interleaved) into LDS: bias[l][unit*4+gate] = b_ih+b_hh
#pragma unroll
  for (int l = 0; l < 2; ++l) {
    int rp = tid;  // 0..511
    int row = (rp & 3) * 128 + (rp >> 2);
    biasS[l * 512 + rp] = b_ih[l * 512 + row] + b_hh[l * 512 + row];
  }
  // zero h0/h1 buffers (both parities)
#pragma unroll
  for (int i = 0; i < 2; ++i)
    *(f32x4*)(sm + tid * 16 + i * 8192) = (f32x4){0.f, 0.f, 0.f, 0.f};
  // load x(t=0) into XT[0]
  {
    int bb = tid >> 5, k4 = (tid & 31) * 4;
    int bg = blockIdx.x * NB + bb;
    f32x4 v = *(const f32x4*)(x + ((size_t)bg * T_INS + 0) * HDIM + k4);
    half4v hx;
    hx[0] = (_Float16)v[0]; hx[1] = (_Float16)v[1];
    hx[2] = (_Float16)v[2]; hx[3] = (_Float16)v[3];
    *(half4v*)(sm + XTO + OFF(bb, k4)) = hx;
  }

  float c0[4] = {0, 0, 0, 0}, c1[4] = {0, 0, 0, 0};
  float hp0[4] = {0, 0, 0, 0}, hp1[4] = {0, 0, 0, 0};
  __syncthreads();

  const int xb = tid >> 5, xk4 = (tid & 31) * 4;
  const int xbg = blockIdx.x * NB + xb;

  for (int t = 0; t < 400; ++t) {
    const int p = t & 1;
    const bool doX = (t < 199);
    f32x4 xpre = (f32x4){0.f, 0.f, 0.f, 0.f};
    if (doX)
      xpre = *(const f32x4*)(x + ((size_t)xbg * T_INS + (t + 1)) * HDIM + xk4);

    const bool mk = (t < 200) ? (t < Lin) : ((t - 200) < Lar);

    // ================= layer 0 =================
    f32x4 acc[4] = {{0, 0, 0, 0}, {0, 0, 0, 0}, {0, 0, 0, 0}, {0, 0, 0, 0}};
    {
      const char* sX = (t < 200) ? (sm + XTO + p * 4096) : (sm + H1O + p * 4096);
      half8 bf[4];
#pragma unroll
      for (int kf = 0; kf < 4; ++kf)
        bf[kf] = *(const half8*)(sX + OFF(lb, kf * 32 + k0b));
      if (packed) {
        const char* ib = ws + (size_t)(w * 16) * 1024 + lane * 16;  // l=0
#pragma unroll
        for (int h2 = 0; h2 < 2; ++h2) {
          half8 s[4][2];
#pragma unroll
          for (int mt = 0; mt < 4; ++mt)
#pragma unroll
            for (int j = 0; j < 2; ++j)
              s[mt][j] = *(const half8*)(ib + (mt * 4 + h2 * 2 + j) * 1024);
#pragma unroll
          for (int mt = 0; mt < 4; ++mt)
#pragma unroll
            for (int j = 0; j < 2; ++j)
              acc[mt] = __builtin_amdgcn_mfma_f32_16x16x32_f16(
                  s[mt][j], bf[h2 * 2 + j], acc[mt], 0, 0, 0);
        }
      } else {
#pragma unroll
        for (int mt = 0; mt < 4; ++mt)
#pragma unroll
          for (int kf = 0; kf < 4; ++kf) {
            half8 s = cvt_frag(W_ih + (size_t)rowi[mt] * 128 + kf * 32 + k0b);
            acc[mt] = __builtin_amdgcn_mfma_f32_16x16x32_f16(s, bf[kf], acc[mt], 0, 0, 0);
          }
      }
      const char* sH = sm + H0O + (p ^ 1) * 4096;  // h0(t-1)
#pragma unroll
      for (int kf = 0; kf < 4; ++kf)
        bf[kf] = *(const half8*)(sH + OFF(lb, kf * 32 + k0b));
#pragma unroll
      for (int mt = 0; mt < 4; ++mt)
#pragma unroll
        for (int kf = 0; kf < 4; ++kf)
          acc[mt] = __builtin_amdgcn_mfma_f32_16x16x32_f16(whh[0][mt][kf], bf[kf],
                                                           acc[mt], 0, 0, 0);
    }
    // ACT0
#pragma unroll
    for (int mt = 0; mt < 4; ++mt) {
      const int u = w * 16 + mt * 4 + lg;
      f32x4 bb = *(const f32x4*)(biasS + u * 4);
      float si = sigm(acc[mt][0] + bb[0]);
      float sf = sigm(acc[mt][1] + bb[1]);
      float tg = tanh_f(acc[mt][2] + bb[2]);
      float so = sigm(acc[mt][3] + bb[3]);
      float cn = sf * c0[mt] + si * tg;
      float hn = so * tanh_f(cn);
      c0[mt] = mk ? cn : c0[mt];
      hp0[mt] = mk ? hn : hp0[mt];
      *(_Float16*)(sm + H0O + p * 4096 + OFF(lb, u)) = (_Float16)hp0[mt];
    }
    __syncthreads();  // h0[p] published

    // stage x(t+1) into XT[p^1]
    if (doX) {
      half4v hx;
      hx[0] = (_Float16)xpre[0]; hx[1] = (_Float16)xpre[1];
      hx[2] = (_Float16)xpre[2]; hx[3] = (_Float16)xpre[3];
      *(half4v*)(sm + XTO + (p ^ 1) * 4096 + OFF(xb, xk4)) = hx;
    }

    // ================= layer 1 =================
#pragma unroll
    for (int mt = 0; mt < 4; ++mt) acc[mt] = (f32x4){0.f, 0.f, 0.f, 0.f};
    {
      const char* sX = sm + H0O + p * 4096;  // fresh h0(t)
      half8 bf[4];
#pragma unroll
      for (int kf = 0; kf < 4; ++kf)
        bf[kf] = *(const half8*)(sX + OFF(lb, kf * 32 + k0b));
      if (packed) {
        const char* ib = ws + (size_t)(128 + w * 16) * 1024 + lane * 16;  // l=1
#pragma unroll
        for (int h2 = 0; h2 < 2; ++h2) {
          half8 s[4][2];
#pragma unroll
          for (int mt = 0; mt < 4; ++mt)
#pragma unroll
            for (int j = 0; j < 2; ++j)
              s[mt][j] = *(const half8*)(ib + (mt * 4 + h2 * 2 + j) * 1024);
#pragma unroll
          for (int mt = 0; mt < 4; ++mt)
#pragma unroll
            for (int j = 0; j < 2; ++j)
              acc[mt] = __builtin_amdgcn_mfma_f32_16x16x32_f16(
                  s[mt][j], bf[h2 * 2 + j], acc[mt], 0, 0, 0);
        }
      } else {
#pragma unroll
        for (int mt = 0; mt < 4; ++mt)
#pragma unroll
          for (int kf = 0; kf < 4; ++kf) {
            half8 s = cvt_frag(W_ih + (size_t)(512 + rowi[mt]) * 128 + kf * 32 + k0b);
            acc[mt] = __builtin_amdgcn_mfma_f32_16x16x32_f16(s, bf[kf], acc[mt], 0, 0, 0);
          }
      }
      const char* sH = sm + H1O + p * 4096;  // h1(t-1)
#pragma unroll
      for (int kf = 0; kf < 4; ++kf)
        bf[kf] = *(const half8*)(sH + OFF(lb, kf * 32 + k0b));
#pragma unroll
      for (int mt = 0; mt < 4; ++mt)
#pragma unroll
        for (int kf = 0; kf < 4; ++kf)
          acc[mt] = __builtin_amdgcn_mfma_f32_16x16x32_f16(whh[1][mt][kf], bf[kf],
                                                           acc[mt], 0, 0, 0);
    }
    // ACT1 + output
#pragma unroll
    for (int mt = 0; mt < 4; ++mt) {
      const int u = w * 16 + mt * 4 + lg;
      f32x4 bb = *(const f32x4*)(biasS + 512 + u * 4);
      float si = sigm(acc[mt][0] + bb[0]);
      float sf = sigm(acc[mt][1] + bb[1]);
      float tg = tanh_f(acc[mt][2] + bb[2]);
      float so = sigm(acc[mt][3] + bb[3]);
      float cn = sf * c1[mt] + si * tg;
      float hn = so * tanh_f(cn);
      c1[mt] = mk ? cn : c1[mt];
      hp1[mt] = mk ? hn : hp1[mt];
      *(_Float16*)(sm + H1O + (p ^ 1) * 4096 + OFF(lb, u)) = (_Float16)hp1[mt];
      float vo = mk ? hn : 0.0f;
      size_t oix;
      if (t < 200)
        oix = (size_t)batch * 25600 + (size_t)t * 128 + u;
      else
        oix = 13107200ull + (size_t)batch * 25600 + (size_t)(t - 200) * 128 + u;
      out[oix] = vo;
    }
    __syncthreads();  // h1[p^1], XT[p^1] published
  }
}

extern "C" void kernel_launch(void* const* d_in, const int* in_sizes, int n_in,
                              void* d_out, int out_size, void* d_ws, size_t ws_size,
                              hipStream_t stream) {
  (void)in_sizes; (void)n_in; (void)out_size;
  const float* x = (const float*)d_in[0];
  const int* len_in = (const int*)d_in[1];
  const int* len_ar = (const int*)d_in[2];
  // d_in[3] = mask_aureg (bool) unused; recomputed from lengths (monotone mask)
  const float* W_ih = (const float*)d_in[4];
  const float* W_hh = (const float*)d_in[5];
  const float* b_ih = (const float*)d_in[6];
  const float* b_hh = (const float*)d_in[7];
  float* out = (float*)d_out;
  char* ws = (char*)d_ws;

  int packed = (ws_size >= (size_t)262144) ? 1 : 0;
  if (packed) pack_kernel<<<dim3(64), dim3(256), 0, stream>>>(W_ih, ws);
  lstm_kernel<<<dim3(32), dim3(512), 0, stream>>>(x, len_in, len_ar, W_ih, W_hh,
                                                  b_ih, b_hh, ws, out, packed);
}